// Round 7
// baseline (10.177 us; speedup 1.0000x reference)
//
#include <hip/hip_runtime.h>
#include <hip/hip_bf16.h>

// Shapes (fixed by the reference):
//   input:       [B=32, S=2048, H=1024] float32
//   number_mask: [B=32, S=2048] int
//   max_number:  scalar 20 -> J = 20 labels (1..20)
//   output:      [B, J, 2H] float32
#define B_DIM 32
#define S_DIM 2048
#define H_DIM 1024
#define J_DIM 20

// One block of 256 per (b, j). R2 structure (scalar coalesced mask loads,
// proven 9.9 us) with ONE change: single-barrier LDS[4] combine instead of
// the two-barrier LDS-atomic combine. Discriminates whether R4's regression
// came from its combine (then this regresses too) or its int4 loads.
__global__ __launch_bounds__(256) void aware_fused_kernel(
        const float* __restrict__ in,
        const int* __restrict__ mask,
        float* __restrict__ out) {
    const int bj    = blockIdx.x;        // b * J + j
    const int b     = bj / J_DIM;
    const int label = bj - b * J_DIM + 1;
    const int t     = threadIdx.x;       // 256 threads = 4 waves

    // --- scan mask row for first/last occurrence of `label` (scalar, coalesced) ---
    int lmin = S_DIM;
    int lmax = -1;
    const int* m = mask + (size_t)b * S_DIM;
    #pragma unroll
    for (int k = 0; k < S_DIM / 256; ++k) {
        int s = t + k * 256;
        int v = m[s];
        if (v == label) {
            lmin = min(lmin, s);
            lmax = max(lmax, s);
        }
    }
    // wave (64-lane) butterfly reduce
    #pragma unroll
    for (int off = 32; off > 0; off >>= 1) {
        lmin = min(lmin, __shfl_down(lmin, off, 64));
        lmax = max(lmax, __shfl_down(lmax, off, 64));
    }
    // cross-wave combine: one barrier, broadcast reads
    __shared__ int swf[4], swl[4];
    if ((t & 63) == 0) {
        swf[t >> 6] = lmin;
        swl[t >> 6] = lmax;
    }
    __syncthreads();
    const int f = min(min(swf[0], swf[1]), min(swf[2], swf[3]));
    const int l = max(max(swl[0], swl[1]), max(swl[2], swl[3]));
    const bool exists = (f < S_DIM);

    // --- gather: H/4 = 256 float4 per half, one per thread ---
    float4* o = reinterpret_cast<float4*>(out + (size_t)bj * (2 * H_DIM));
    if (exists) {
        const float4* src_f = reinterpret_cast<const float4*>(
            in + ((size_t)b * S_DIM + f) * H_DIM);
        const float4* src_l = reinterpret_cast<const float4*>(
            in + ((size_t)b * S_DIM + l) * H_DIM);
        o[t]             = src_f[t];
        o[t + H_DIM / 4] = src_l[t];
    } else {
        float4 z; z.x = 0.f; z.y = 0.f; z.z = 0.f; z.w = 0.f;
        o[t]             = z;
        o[t + H_DIM / 4] = z;
    }
}

extern "C" void kernel_launch(void* const* d_in, const int* in_sizes, int n_in,
                              void* d_out, int out_size, void* d_ws, size_t ws_size,
                              hipStream_t stream) {
    const float* input = (const float*)d_in[0];
    const int*   mask  = (const int*)d_in[1];
    float*       out   = (float*)d_out;

    aware_fused_kernel<<<B_DIM * J_DIM, 256, 0, stream>>>(input, mask, out);
}